// Round 2
// baseline (335.246 us; speedup 1.0000x reference)
//
#include <hip/hip_runtime.h>
#include <hip/hip_bf16.h>

// Problem constants (B=8, N=256, DIN=DOUT=EIN=EOUT=64)
#define BN   2048      // B*N
#define NN   256       // N
#define CH   64        // channel dims

typedef __attribute__((ext_vector_type(8))) short short8;   // 8 bf16 (4 VGPRs)
typedef __attribute__((ext_vector_type(4))) float fv4;      // 4 fp32

// fp32 -> bf16 bits, round-to-nearest-even
static __device__ inline short f2bf(float f) {
  unsigned u = __float_as_uint(f);
  u += 0x7FFF + ((u >> 16) & 1);
  return (short)(u >> 16);
}

// ---------------------------------------------------------------------------
// Kernel 1 (unchanged, tiny): node_x = emb_node@Wn + bn (fp32 -> ws)
//                             rsx    = relu(emb_node@Wsn + bsn) (fp32 -> ws)
// ---------------------------------------------------------------------------
__global__ __launch_bounds__(256) void node_kernel(
    const float* __restrict__ emb_node, const float* __restrict__ Wn,
    const float* __restrict__ bn, const float* __restrict__ Wsn,
    const float* __restrict__ bsn, float* __restrict__ node_x,
    float* __restrict__ rsx) {
  __shared__ float s_emb[4][CH];
  const int r = threadIdx.x >> 6;
  const int c = threadIdx.x & 63;
  const int row = blockIdx.x * 4 + r;
  s_emb[r][c] = emb_node[row * CH + c];
  __syncthreads();
  float a1 = bn[c], a2 = bsn[c];
#pragma unroll
  for (int k = 0; k < CH; ++k) {
    const float e = s_emb[r][k];
    a1 = fmaf(e, Wn[k * CH + c], a1);
    a2 = fmaf(e, Wsn[k * CH + c], a2);
  }
  node_x[row * CH + c] = a1;
  rsx[row * CH + c] = fmaxf(a2, 0.0f);
}

// ---------------------------------------------------------------------------
// Kernel 2: MFMA edge GEMM + fused masked aggregation. No LDS, no barriers.
// Block = (b,i); 4 waves; wave w owns cols [16w,16w+16). Each wave iterates
// 16 j-tiles (16 rows each), 2x mfma_f32_16x16x32_bf16 per tile (K=64).
// A-frag:  lane holds emb_edge[j0 + (lane&15)][k = h*32 + quad*8 + 0..7]
//          -> two float4 global loads (coalesced, full-cacheline coverage).
// B-frag:  We column slice, converted to bf16 once, lives in VGPRs.
// C/D:     col = c0+(lane&15), row = j0 + quad*4 + reg   [m89-verified]
// Epilogue per reg: ex = acc[r]+be[c]; edge_out = relu(ex);
//                   agg += A[b,i,row]*ex*node_x[b,row,c]  (pre-relu ex!)
// Cross-quad reduce via shfl_xor(16,32); quad 0 writes node_out.
// ---------------------------------------------------------------------------
__global__ __launch_bounds__(256) void edge_mfma_kernel(
    const float* __restrict__ A, const float* __restrict__ emb_edge,
    const float* __restrict__ We, const float* __restrict__ be,
    const float* __restrict__ node_x, const float* __restrict__ rsx,
    float* __restrict__ node_out, float* __restrict__ edge_out) {
  const int bi   = blockIdx.x;         // b*N + i
  const int b    = bi >> 8;
  const int lane = threadIdx.x & 63;
  const int wave = threadIdx.x >> 6;   // 0..3 -> col tile
  const int l15  = lane & 15;
  const int quad = lane >> 4;
  const int c    = wave * 16 + l15;    // this lane's output channel

  // --- B fragments: We[k, c] -> bf16, k = h*32 + quad*8 + j ---
  short8 bfrag[2];
#pragma unroll
  for (int h = 0; h < 2; ++h)
#pragma unroll
    for (int j = 0; j < 8; ++j)
      bfrag[h][j] = f2bf(We[(h * 32 + quad * 8 + j) * CH + c]);
  const float bias = be[c];

  const float* __restrict__ ee   = emb_edge + (size_t)bi * NN * CH;
  float*       __restrict__ eo   = edge_out + (size_t)bi * NN * CH;
  const float* __restrict__ Arow = A + (size_t)bi * NN;
  const float* __restrict__ nx   = node_x + (size_t)b * NN * CH;

  float agg = 0.0f;

#pragma unroll 4
  for (int jt = 0; jt < 16; ++jt) {
    const int j0 = jt * 16;
    fv4 acc = {0.0f, 0.0f, 0.0f, 0.0f};
#pragma unroll
    for (int h = 0; h < 2; ++h) {
      const float* p = ee + (size_t)(j0 + l15) * CH + h * 32 + quad * 8;
      const fv4 v0 = *(const fv4*)p;
      const fv4 v1 = *(const fv4*)(p + 4);
      short8 af;
      af[0] = f2bf(v0[0]); af[1] = f2bf(v0[1]);
      af[2] = f2bf(v0[2]); af[3] = f2bf(v0[3]);
      af[4] = f2bf(v1[0]); af[5] = f2bf(v1[1]);
      af[6] = f2bf(v1[2]); af[7] = f2bf(v1[3]);
      acc = __builtin_amdgcn_mfma_f32_16x16x32_bf16(af, bfrag[h], acc, 0, 0, 0);
    }
#pragma unroll
    for (int r = 0; r < 4; ++r) {
      const int row = j0 + quad * 4 + r;
      const float ex = acc[r] + bias;                 // pre-relu edge_x
      eo[row * CH + c] = fmaxf(ex, 0.0f);
      agg = fmaf(Arow[row] * ex, nx[row * CH + c], agg);
    }
  }

  // reduce the per-quad partials (same col c lives at lane^16, lane^32)
  agg += __shfl_xor(agg, 16, 64);
  agg += __shfl_xor(agg, 32, 64);
  if (quad == 0) {
    node_out[(size_t)bi * CH + c] =
        fmaxf(agg, 0.0f) + rsx[(size_t)bi * CH + c];
  }
}

// ---------------------------------------------------------------------------
extern "C" void kernel_launch(void* const* d_in, const int* in_sizes, int n_in,
                              void* d_out, int out_size, void* d_ws, size_t ws_size,
                              hipStream_t stream) {
  const float* A        = (const float*)d_in[0];  // [8,256,256]
  const float* emb_node = (const float*)d_in[1];  // [8,256,64]
  const float* emb_edge = (const float*)d_in[2];  // [8,256,256,64]
  const float* Wn       = (const float*)d_in[3];  // [64,64]
  const float* bn       = (const float*)d_in[4];  // [64]
  const float* Wsn      = (const float*)d_in[5];  // [64,64]
  const float* bsn      = (const float*)d_in[6];  // [64]
  const float* We       = (const float*)d_in[7];  // [64,64]
  const float* be       = (const float*)d_in[8];  // [64]

  float* node_out = (float*)d_out;                     // [2048,64]
  float* edge_out = (float*)d_out + (size_t)BN * CH;   // [2048,256,64]

  float* node_x = (float*)d_ws;                        // [2048,64] fp32
  float* rsx    = (float*)d_ws + (size_t)BN * CH;      // [2048,64] fp32

  hipLaunchKernelGGL(node_kernel, dim3(BN / 4), dim3(256), 0, stream,
                     emb_node, Wn, bn, Wsn, bsn, node_x, rsx);
  hipLaunchKernelGGL(edge_mfma_kernel, dim3(BN), dim3(256), 0, stream,
                     A, emb_edge, We, be, node_x, rsx, node_out, edge_out);
}

// Round 3
// 259.388 us; speedup vs baseline: 1.2925x; 1.2925x over previous
//
#include <hip/hip_runtime.h>
#include <hip/hip_bf16.h>

// Problem constants (B=8, N=256, DIN=DOUT=EIN=EOUT=64)
#define BN   2048      // B*N
#define NN   256       // N
#define CH   64        // channel dims
#define RPC  32        // rows per staged chunk
#define NCHK 8         // chunks per block (256/32)
#define LDST 88        // LDS row stride in bf16 elems (176 B: 16B-aligned rows, 2-way banks)

typedef __attribute__((ext_vector_type(8))) short short8;   // 8 bf16
typedef __attribute__((ext_vector_type(4))) short short4v;  // 4 bf16
typedef __attribute__((ext_vector_type(4))) float fv4;

// fp32 -> bf16 bits, round-to-nearest-even
static __device__ inline short f2bf(float f) {
  unsigned u = __float_as_uint(f);
  u += 0x7FFF + ((u >> 16) & 1);
  return (short)(u >> 16);
}
static __device__ inline short4v cvt4(fv4 v) {
  short4v r;
  r[0] = f2bf(v[0]); r[1] = f2bf(v[1]); r[2] = f2bf(v[2]); r[3] = f2bf(v[3]);
  return r;
}

// ---------------------------------------------------------------------------
// Kernel 1: node_x = emb_node@Wn + bn (fp32), rsx = relu(emb_node@Wsn + bsn).
// W matrices staged in LDS once per block (kills 128 in-loop global loads per
// thread); emb row broadcast from LDS. grid 512 x 256, 4 rows/block.
// ---------------------------------------------------------------------------
__global__ __launch_bounds__(256) void node_kernel(
    const float* __restrict__ emb_node, const float* __restrict__ Wn,
    const float* __restrict__ bn, const float* __restrict__ Wsn,
    const float* __restrict__ bsn, float* __restrict__ node_x,
    float* __restrict__ rsx) {
  __shared__ float s_emb[4][CH];
  __shared__ float s_Wn[CH * CH];   // 16 KB
  __shared__ float s_Ws[CH * CH];   // 16 KB
  const int tid = threadIdx.x;
  const int r = tid >> 6;
  const int c = tid & 63;
  const int row = blockIdx.x * 4 + r;
  // stage W: 4096 floats each / 256 threads = 4 fv4 per thread per matrix
#pragma unroll
  for (int i = 0; i < 4; ++i) {
    *(fv4*)&s_Wn[(i * 256 + tid) * 4] = *(const fv4*)&Wn[(i * 256 + tid) * 4];
    *(fv4*)&s_Ws[(i * 256 + tid) * 4] = *(const fv4*)&Wsn[(i * 256 + tid) * 4];
  }
  s_emb[r][c] = emb_node[row * CH + c];
  __syncthreads();
  float a1 = bn[c], a2 = bsn[c];
#pragma unroll
  for (int k = 0; k < CH; ++k) {
    const float e = s_emb[r][k];          // wave-uniform broadcast
    a1 = fmaf(e, s_Wn[k * CH + c], a1);   // stride-1: 2-way = free
    a2 = fmaf(e, s_Ws[k * CH + c], a2);
  }
  node_x[row * CH + c] = a1;
  rsx[row * CH + c] = fmaxf(a2, 0.0f);
}

// ---------------------------------------------------------------------------
// Kernel 2: per block (b,i). Double-buffered staging: 32-row chunks of
// emb_edge loaded coalesced (fv4), converted to bf16 once per block, written
// to padded LDS; MFMA consumes via single ds_read_b128 per fragment.
//   edge_x[j,c] = emb[j,:]@We[:,c] + be[c];  edge_out = relu(edge_x)
//   agg[c] += A[j]*edge_x[j,c]*node_x[b,j,c]  (pre-relu edge_x)
// Wave w owns cols [16w,16w+16). C/D: col=lane&15, row=quad*4+reg (m89).
// One barrier per chunk; staging loads for chunk k+1 in flight during
// compute of chunk k.
// ---------------------------------------------------------------------------
__global__ __launch_bounds__(256) void edge_mfma_kernel(
    const float* __restrict__ A, const float* __restrict__ emb_edge,
    const float* __restrict__ We, const float* __restrict__ be,
    const float* __restrict__ node_x, const float* __restrict__ rsx,
    float* __restrict__ node_out, float* __restrict__ edge_out) {
  const int bi   = blockIdx.x;         // b*N + i
  const int b    = bi >> 8;
  const int tid  = threadIdx.x;
  const int lane = tid & 63;
  const int wave = tid >> 6;           // 0..3 -> col tile
  const int l15  = lane & 15;
  const int quad = lane >> 4;
  const int c    = wave * 16 + l15;

  __shared__ __align__(16) short sbuf[2][RPC * LDST];  // 2 x 5632 B bf16
  __shared__ float s_A[NN];                            // 1 KB

  // B fragments: We[k,c] -> bf16 in VGPRs, k = h*32 + quad*8 + j
  short8 bfrag[2];
#pragma unroll
  for (int h = 0; h < 2; ++h)
#pragma unroll
    for (int j = 0; j < 8; ++j)
      bfrag[h][j] = f2bf(We[(h * 32 + quad * 8 + j) * CH + c]);
  const float bias = be[c];

  const float* __restrict__ ee = emb_edge + (size_t)bi * NN * CH;
  float*       __restrict__ eo = edge_out + (size_t)bi * NN * CH;
  const float* __restrict__ nx = node_x + (size_t)b * NN * CH;

  s_A[tid] = A[(size_t)bi * NN + tid];

  // staging geometry: iter i handles element idx = i*256+tid ->
  //   row = i*16 + (tid>>4), kcol = (tid&15)*4   (4 floats, same row)
  const int srow = tid >> 4;
  const int kcol = (tid & 15) * 4;

  // preload chunk 0
  fv4 st0 = *(const fv4*)(ee + tid * 4);
  fv4 st1 = *(const fv4*)(ee + 1024 + tid * 4);
  *(short4v*)&sbuf[0][srow * LDST + kcol] = cvt4(st0);
  *(short4v*)&sbuf[0][(16 + srow) * LDST + kcol] = cvt4(st1);

  float agg = 0.0f;

#pragma unroll 2
  for (int ch = 0; ch < NCHK; ++ch) {
    const int pb = ch & 1;
    // issue loads for next chunk (in flight across barrier + compute)
    if (ch + 1 < NCHK) {
      const float* cb = ee + (ch + 1) * (RPC * CH);
      st0 = *(const fv4*)(cb + tid * 4);
      st1 = *(const fv4*)(cb + 1024 + tid * 4);
    }
    __syncthreads();   // sbuf[pb] now holds chunk ch

#pragma unroll
    for (int half = 0; half < 2; ++half) {
      const int j0l = half * 16;
      const int j0  = ch * RPC + j0l;
      // prefetch epilogue operands early
      const fv4 av = *(const fv4*)&s_A[j0 + quad * 4];   // broadcast per quad
      float nxv[4];
#pragma unroll
      for (int r = 0; r < 4; ++r)
        nxv[r] = nx[(j0 + quad * 4 + r) * CH + c];       // L2-resident
      const short8 af0 =
          *(const short8*)&sbuf[pb][(j0l + l15) * LDST + quad * 8];
      const short8 af1 =
          *(const short8*)&sbuf[pb][(j0l + l15) * LDST + 32 + quad * 8];
      fv4 acc = {0.0f, 0.0f, 0.0f, 0.0f};
      acc = __builtin_amdgcn_mfma_f32_16x16x32_bf16(af0, bfrag[0], acc, 0, 0, 0);
      acc = __builtin_amdgcn_mfma_f32_16x16x32_bf16(af1, bfrag[1], acc, 0, 0, 0);
#pragma unroll
      for (int r = 0; r < 4; ++r) {
        const int row = j0 + quad * 4 + r;
        const float ex = acc[r] + bias;                  // pre-relu edge_x
        eo[row * CH + c] = fmaxf(ex, 0.0f);
        agg = fmaf(av[r] * ex, nxv[r], agg);
      }
    }

    // write next chunk to the other buffer (current readers use sbuf[pb])
    if (ch + 1 < NCHK) {
      *(short4v*)&sbuf[pb ^ 1][srow * LDST + kcol] = cvt4(st0);
      *(short4v*)&sbuf[pb ^ 1][(16 + srow) * LDST + kcol] = cvt4(st1);
    }
  }

  // reduce per-quad partials (same col c at lane^16, lane^32)
  agg += __shfl_xor(agg, 16, 64);
  agg += __shfl_xor(agg, 32, 64);
  if (quad == 0) {
    node_out[(size_t)bi * CH + c] =
        fmaxf(agg, 0.0f) + rsx[(size_t)bi * CH + c];
  }
}

// ---------------------------------------------------------------------------
extern "C" void kernel_launch(void* const* d_in, const int* in_sizes, int n_in,
                              void* d_out, int out_size, void* d_ws, size_t ws_size,
                              hipStream_t stream) {
  const float* A        = (const float*)d_in[0];  // [8,256,256]
  const float* emb_node = (const float*)d_in[1];  // [8,256,64]
  const float* emb_edge = (const float*)d_in[2];  // [8,256,256,64]
  const float* Wn       = (const float*)d_in[3];  // [64,64]
  const float* bn       = (const float*)d_in[4];  // [64]
  const float* Wsn      = (const float*)d_in[5];  // [64,64]
  const float* bsn      = (const float*)d_in[6];  // [64]
  const float* We       = (const float*)d_in[7];  // [64,64]
  const float* be       = (const float*)d_in[8];  // [64]

  float* node_out = (float*)d_out;                     // [2048,64]
  float* edge_out = (float*)d_out + (size_t)BN * CH;   // [2048,256,64]

  float* node_x = (float*)d_ws;                        // [2048,64] fp32
  float* rsx    = (float*)d_ws + (size_t)BN * CH;      // [2048,64] fp32

  hipLaunchKernelGGL(node_kernel, dim3(BN / 4), dim3(256), 0, stream,
                     emb_node, Wn, bn, Wsn, bsn, node_x, rsx);
  hipLaunchKernelGGL(edge_mfma_kernel, dim3(BN), dim3(256), 0, stream,
                     A, emb_edge, We, be, node_x, rsx, node_out, edge_out);
}